// Round 3
// baseline (479.499 us; speedup 1.0000x reference)
//
#include <hip/hip_runtime.h>
#include <hip/hip_bf16.h>

typedef __attribute__((ext_vector_type(8))) short short8;
typedef __attribute__((ext_vector_type(4))) float f32x4;

#define B_  32
#define S_  484
#define E_  1024
#define NH  16
#define SP  512          // padded sequence length
#define M_  (B_*S_)      // 15488 = 121*128

static __device__ __forceinline__ ushort f2bf(float f) {
  union { float f; unsigned u; } v; v.f = f;
  unsigned u = v.u;
  return (ushort)((u + 0x7FFFu + ((u >> 16) & 1u)) >> 16);
}

#define GLOAD_LDS16(gp, lp) \
  __builtin_amdgcn_global_load_lds((const __attribute__((address_space(1))) void*)(gp), \
                                   (__attribute__((address_space(3))) void*)(lp), 16, 0, 0)

// ---------------- f32 -> bf16 flat convert (vectorized) ----------------
__global__ __launch_bounds__(256)
void cvt_f32_bf16(const float* __restrict__ x, ushort* __restrict__ y, int n4) {
  int i = blockIdx.x * 256 + threadIdx.x;
  int stride = gridDim.x * 256;
  for (; i < n4; i += stride) {
    float4 v = ((const float4*)x)[i];
    ushort4 h;
    h.x = f2bf(v.x); h.y = f2bf(v.y); h.z = f2bf(v.z); h.w = f2bf(v.w);
    ((ushort4*)y)[i] = h;
  }
}

// ---------------- weight transpose + convert: WT[n][k] = W[k][n] ----------------
__global__ __launch_bounds__(256)
void transpose_convert(const float* __restrict__ W, ushort* __restrict__ WT, int K, int N) {
  __shared__ float tile[32][33];
  int k0 = blockIdx.y * 32, n0 = blockIdx.x * 32;
  int tx = threadIdx.x, ty = threadIdx.y;   // 32 x 8
  for (int i = ty; i < 32; i += 8) tile[i][tx] = W[(size_t)(k0 + i) * N + n0 + tx];
  __syncthreads();
  for (int i = ty; i < 32; i += 8) WT[(size_t)(n0 + i) * K + k0 + tx] = f2bf(tile[tx][i]);
}

// ---------------- bf16 GEMM, B^T input, 128x128 tile, m97 structure ----------------
template<int EPI>
__global__ __launch_bounds__(256)
void gemm_bt(const ushort* __restrict__ A, const ushort* __restrict__ BT,
             void* __restrict__ Cout, int N, int K, int HN, float oscale) {
  __shared__ alignas(16) ushort sA[2][128 * 32];
  __shared__ alignas(16) ushort sB[2][128 * 32];
  const int tid = threadIdx.x;
  const int lane = tid & 63, w = tid >> 6;
  const int m0 = blockIdx.y * 128, n0 = blockIdx.x * 128;
  const int NK = K >> 5;

  const int srow = w * 32 + (lane >> 2);
  const int scol = (lane & 3) * 8;
  const ushort* gA0 = A  + (size_t)(m0 + srow) * K + scol;
  const ushort* gB0 = BT + (size_t)(n0 + srow) * K + scol;

  const int wr = w >> 1, wc = w & 1;          // 2x2 wave grid, each 64x64
  const int g4 = lane >> 4, l16 = lane & 15;
  const int aoff = (wr * 64 + l16) * 32 + 8 * g4;
  const int boff = (wc * 64 + l16) * 32 + 8 * g4;

  f32x4 acc[4][4] = {};

  {
    const ushort* ga = gA0; const ushort* gb = gB0;
    GLOAD_LDS16(ga,            &sA[0][(w * 32) * 32]);
    GLOAD_LDS16(ga + 16 * K,   &sA[0][(w * 32 + 16) * 32]);
    GLOAD_LDS16(gb,            &sB[0][(w * 32) * 32]);
    GLOAD_LDS16(gb + 16 * K,   &sB[0][(w * 32 + 16) * 32]);
  }

  for (int kt = 0; kt < NK; ++kt) {
    __syncthreads();
    if (kt + 1 < NK) {
      int nb = (kt + 1) & 1;
      const ushort* ga = gA0 + (kt + 1) * 32;
      const ushort* gb = gB0 + (kt + 1) * 32;
      GLOAD_LDS16(ga,            &sA[nb][(w * 32) * 32]);
      GLOAD_LDS16(ga + 16 * K,   &sA[nb][(w * 32 + 16) * 32]);
      GLOAD_LDS16(gb,            &sB[nb][(w * 32) * 32]);
      GLOAD_LDS16(gb + 16 * K,   &sB[nb][(w * 32 + 16) * 32]);
    }
    const ushort* pa = &sA[kt & 1][aoff];
    const ushort* pb = &sB[kt & 1][boff];
    short8 af[4], bf[4];
#pragma unroll
    for (int i = 0; i < 4; ++i) {
      af[i] = *(const short8*)(pa + i * 16 * 32);
      bf[i] = *(const short8*)(pb + i * 16 * 32);
    }
#pragma unroll
    for (int mi = 0; mi < 4; ++mi)
#pragma unroll
      for (int ni = 0; ni < 4; ++ni)
        acc[mi][ni] = __builtin_amdgcn_mfma_f32_16x16x32_bf16(af[mi], bf[ni], acc[mi][ni], 0, 0, 0);
  }

#pragma unroll
  for (int mi = 0; mi < 4; ++mi) {
#pragma unroll
    for (int ni = 0; ni < 4; ++ni) {
#pragma unroll
      for (int r = 0; r < 4; ++r) {
        int m = m0 + wr * 64 + mi * 16 + g4 * 4 + r;
        int n = n0 + wc * 64 + ni * 16 + l16;
        float vv = acc[mi][ni][r];
        if (EPI == 2) {
          ((float*)Cout)[(size_t)m * N + n] = vv;
        } else {
          int b = m / S_, pos = m % S_;
          if (EPI == 0) {
            ushort hv = f2bf(vv * oscale);
            ((ushort*)Cout)[(((size_t)b * HN + (n >> 6)) * SP + pos) * 64 + (n & 63)] = hv;
          } else {
            ushort hv = f2bf(vv);
            ((ushort*)Cout)[(((size_t)b * HN + (n >> 6)) * 64 + (n & 63)) * SP + pos] = hv;
          }
        }
      }
    }
  }
}

// ---------------- fused GQA attention, no-max softmax, reg-pipelined K/V ----------------
// 1D grid 4096, XCD swizzle: XCD x owns batches 4x..4x+3 (K/V slab 2MB -> L2-resident)
// block 256 = 4 waves, wave = 16 q-rows; qp pre-scaled by 0.125*log2e, bias*log2e staged
__global__ __launch_bounds__(256)
void attn_kernel(const ushort* __restrict__ qp, const ushort* __restrict__ kp,
                 const ushort* __restrict__ vpT, const float* __restrict__ rel,
                 ushort* __restrict__ ao) {
  __shared__ float sBias[1024];
  __shared__ alignas(16) ushort sP[4][16 * 40];
  const int tid = threadIdx.x;
  const int d = blockIdx.x;
  const int logical = (d & 7) * 512 + (d >> 3);     // bijective (4096 = 8*512)
  const int qt = logical & 7, head = (logical >> 3) & 15, b = logical >> 7;
  const int g = head >> 2;
  const float LOG2E = 1.44269504f;
  for (int t = tid; t < 1024; t += 256)
    sBias[t] = (t < 967) ? rel[t * 16 + head] * LOG2E : -1e30f;
  __syncthreads();

  const int lane = tid & 63, w = tid >> 6;
  const int g4 = lane >> 4, l16 = lane & 15;
  const int qw = qt * 64 + w * 16;

  const ushort* qbase = qp + (((size_t)b * NH + head) * SP + qw + l16) * 64;
  short8 qf0 = *(const short8*)(qbase + 8 * g4);
  short8 qf1 = *(const short8*)(qbase + 32 + 8 * g4);
  const ushort* kbase = kp + ((size_t)b * 4 + g) * SP * 64 + (size_t)l16 * 64 + 8 * g4;
  const ushort* vbase = vpT + ((size_t)b * 4 + g) * 64 * SP + (size_t)l16 * SP + 8 * g4;

  f32x4 acc[4] = {};
  float ps[4] = {0.f, 0.f, 0.f, 0.f};
  const int ib = l16 - (qw + g4 * 4) + 483;   // bias idx for r=0, k0=0
  ushort* sPw = &sP[w][0];

  auto loadKV = [&](int kt, short8 (&kf)[4], short8 (&vf)[4]) {
    const int k0 = kt * 32;
    const ushort* kp0 = kbase + (size_t)k0 * 64;
    kf[0] = *(const short8*)(kp0);
    kf[1] = *(const short8*)(kp0 + 32);
    kf[2] = *(const short8*)(kp0 + 16 * 64);
    kf[3] = *(const short8*)(kp0 + 16 * 64 + 32);
    const ushort* vp0 = vbase + k0;
#pragma unroll
    for (int nt = 0; nt < 4; ++nt) vf[nt] = *(const short8*)(vp0 + nt * 16 * SP);
  };

  auto compute = [&](int kt, short8 (&kf)[4], short8 (&vf)[4], bool maskTail) {
    const int k0 = kt * 32;
    f32x4 s0 = {}, s1 = {};
    s0 = __builtin_amdgcn_mfma_f32_16x16x32_bf16(qf0, kf[0], s0, 0, 0, 0);
    s0 = __builtin_amdgcn_mfma_f32_16x16x32_bf16(qf1, kf[1], s0, 0, 0, 0);
    s1 = __builtin_amdgcn_mfma_f32_16x16x32_bf16(qf0, kf[2], s1, 0, 0, 0);
    s1 = __builtin_amdgcn_mfma_f32_16x16x32_bf16(qf1, kf[3], s1, 0, 0, 0);
#pragma unroll
    for (int r = 0; r < 4; ++r) {
      int i0 = ib + k0 - r;
      float p0 = __builtin_amdgcn_exp2f(s0[r] + sBias[i0]);
      float p1 = __builtin_amdgcn_exp2f(s1[r] + sBias[i0 + 16]);
      s0[r] = p0; s1[r] = p1;
      if (maskTail) {
        p0 = (k0 + l16 < S_) ? p0 : 0.f;
        p1 = (k0 + 16 + l16 < S_) ? p1 : 0.f;
      }
      ps[r] += p0 + p1;
    }
#pragma unroll
    for (int r = 0; r < 4; ++r) {
      int row = g4 * 4 + r;
      sPw[row * 40 + l16]      = f2bf(s0[r]);
      sPw[row * 40 + 16 + l16] = f2bf(s1[r]);
    }
    short8 pf = *(const short8*)(sPw + l16 * 40 + 8 * g4);
#pragma unroll
    for (int nt = 0; nt < 4; ++nt)
      acc[nt] = __builtin_amdgcn_mfma_f32_16x16x32_bf16(pf, vf[nt], acc[nt], 0, 0, 0);
  };

  // software pipeline: loads for tile t+1 issued before compute of tile t
  short8 kA[4], vA[4], kB[4], vB[4];
  loadKV(0, kA, vA);
#pragma unroll
  for (int kt = 0; kt < 16; kt += 2) {
    if (kt + 1 < 16) loadKV(kt + 1, kB, vB);
    compute(kt, kA, vA, false);
    if (kt + 2 < 16) loadKV(kt + 2, kA, vA);
    compute(kt + 1, kB, vB, kt + 1 == 15);
  }

  // row-sum reduce across the 16-lane group (once, outside the k-loop)
#pragma unroll
  for (int off = 1; off < 16; off <<= 1) {
#pragma unroll
    for (int r = 0; r < 4; ++r) ps[r] += __shfl_xor(ps[r], off, 64);
  }

#pragma unroll
  for (int r = 0; r < 4; ++r) {
    int q_abs = qw + g4 * 4 + r;
    if (q_abs < S_) {
      float inv = 1.f / ps[r];
#pragma unroll
      for (int nt = 0; nt < 4; ++nt) {
        int dd = nt * 16 + l16;
        ao[((size_t)b * S_ + q_abs) * 1024 + head * 64 + dd] = f2bf(acc[nt][r] * inv);
      }
    }
  }
}

extern "C" void kernel_launch(void* const* d_in, const int* in_sizes, int n_in,
                              void* d_out, int out_size, void* d_ws, size_t ws_size,
                              hipStream_t stream) {
  const float* query = (const float*)d_in[0];
  const float* key   = (const float*)d_in[1];
  const float* value = (const float*)d_in[2];
  const float* Wq    = (const float*)d_in[3];
  const float* Wk    = (const float*)d_in[4];
  const float* Wv    = (const float*)d_in[5];
  const float* Wo    = (const float*)d_in[6];
  const float* rel   = (const float*)d_in[7];

  char* ws = (char*)d_ws;
  size_t off = 0;
  auto alloc = [&](size_t bytes) { char* p = ws + off; off += (bytes + 255) & ~(size_t)255; return p; };

  const size_t MEelems = (size_t)M_ * E_;             // 15,859,712
  ushort* qb  = (ushort*)alloc(MEelems * 2);
  ushort* kb  = (ushort*)alloc(MEelems * 2);
  ushort* vb  = (ushort*)alloc(MEelems * 2);
  ushort* wqT = (ushort*)alloc((size_t)1024 * 1024 * 2);
  ushort* wkT = (ushort*)alloc((size_t)256 * 1024 * 2);
  ushort* wvT = (ushort*)alloc((size_t)256 * 1024 * 2);
  ushort* woT = (ushort*)alloc((size_t)1024 * 1024 * 2);
  ushort* qp  = (ushort*)alloc((size_t)B_ * NH * SP * 64 * 2);   // 32 MB
  ushort* kp  = (ushort*)alloc((size_t)B_ * 4 * SP * 64 * 2);    // 8 MB
  ushort* vp  = (ushort*)alloc((size_t)B_ * 4 * 64 * SP * 2);    // 8 MB
  ushort* ao  = (ushort*)alloc(MEelems * 2);

  const int n4 = (int)(MEelems / 4);
  cvt_f32_bf16<<<2048, 256, 0, stream>>>(query, qb, n4);
  cvt_f32_bf16<<<2048, 256, 0, stream>>>(key,   kb, n4);
  cvt_f32_bf16<<<2048, 256, 0, stream>>>(value, vb, n4);

  transpose_convert<<<dim3(32, 32), dim3(32, 8), 0, stream>>>(Wq, wqT, 1024, 1024);
  transpose_convert<<<dim3(8, 32),  dim3(32, 8), 0, stream>>>(Wk, wkT, 1024, 256);
  transpose_convert<<<dim3(8, 32),  dim3(32, 8), 0, stream>>>(Wv, wvT, 1024, 256);
  transpose_convert<<<dim3(32, 32), dim3(32, 8), 0, stream>>>(Wo, woT, 1024, 1024);

  // qp, kp, vp are contiguous in ws: one memset covers all three (32+8+8 MB)
  hipMemsetAsync(qp, 0, (size_t)B_ * NH * SP * 64 * 2 +
                        (size_t)B_ * 4 * SP * 64 * 2 +
                        (size_t)B_ * 4 * 64 * SP * 2, stream);

  const float QSCALE = 0.125f * 1.44269504f;   // fold 1/sqrt(D) and log2e into q
  gemm_bt<0><<<dim3(8, 121), 256, 0, stream>>>(qb, wqT, qp, 1024, 1024, NH, QSCALE);
  gemm_bt<0><<<dim3(2, 121), 256, 0, stream>>>(kb, wkT, kp, 256, 1024, 4, 1.0f);
  gemm_bt<1><<<dim3(2, 121), 256, 0, stream>>>(vb, wvT, vp, 256, 1024, 4, 1.0f);

  attn_kernel<<<4096, 256, 0, stream>>>(qp, kp, vp, rel, ao);

  gemm_bt<2><<<dim3(8, 121), 256, 0, stream>>>(ao, woT, d_out, 1024, 1024, 0, 1.0f);
}

// Round 4
// 315.269 us; speedup vs baseline: 1.5209x; 1.5209x over previous
//
#include <hip/hip_runtime.h>
#include <hip/hip_bf16.h>

typedef __attribute__((ext_vector_type(8))) short short8;
typedef __attribute__((ext_vector_type(4))) float f32x4;

#define B_  32
#define S_  484
#define E_  1024
#define NH  16
#define SP  512          // padded sequence length
#define M_  (B_*S_)      // 15488 = 121*128

static __device__ __forceinline__ ushort f2bf(float f) {
  union { float f; unsigned u; } v; v.f = f;
  unsigned u = v.u;
  return (ushort)((u + 0x7FFFu + ((u >> 16) & 1u)) >> 16);
}

#define GLOAD_LDS16(gp, lp) \
  __builtin_amdgcn_global_load_lds((const __attribute__((address_space(1))) void*)(gp), \
                                   (__attribute__((address_space(3))) void*)(lp), 16, 0, 0)

// ---------------- f32 -> bf16 flat convert (vectorized) ----------------
__global__ __launch_bounds__(256)
void cvt_f32_bf16(const float* __restrict__ x, ushort* __restrict__ y, int n4) {
  int i = blockIdx.x * 256 + threadIdx.x;
  int stride = gridDim.x * 256;
  for (; i < n4; i += stride) {
    float4 v = ((const float4*)x)[i];
    ushort4 h;
    h.x = f2bf(v.x); h.y = f2bf(v.y); h.z = f2bf(v.z); h.w = f2bf(v.w);
    ((ushort4*)y)[i] = h;
  }
}

// ---------------- weight transpose + convert: WT[n][k] = W[k][n] ----------------
__global__ __launch_bounds__(256)
void transpose_convert(const float* __restrict__ W, ushort* __restrict__ WT, int K, int N) {
  __shared__ float tile[32][33];
  int k0 = blockIdx.y * 32, n0 = blockIdx.x * 32;
  int tx = threadIdx.x, ty = threadIdx.y;   // 32 x 8
  for (int i = ty; i < 32; i += 8) tile[i][tx] = W[(size_t)(k0 + i) * N + n0 + tx];
  __syncthreads();
  for (int i = ty; i < 32; i += 8) WT[(size_t)(n0 + i) * K + k0 + tx] = f2bf(tile[tx][i]);
}

// ---------------- bf16 GEMM, B^T input, 128x128 tile, m97 structure ----------------
// EPI 0: bf16 out (scaled), layout ((b*HN + h)*SP + pos)*64 + d   [+ SWZ: d ^= (pos&7)<<3]
// EPI 1: bf16 out, layout ((b*HN + h)*64 + d)*SP + pos            [+ SWZ: pos ^= (d&3)<<3]
// EPI 2: f32 out, row-major [M][N]
template<int EPI, int SWZ>
__global__ __launch_bounds__(256)
void gemm_bt(const ushort* __restrict__ A, const ushort* __restrict__ BT,
             void* __restrict__ Cout, int N, int K, int HN, float oscale) {
  __shared__ alignas(16) ushort sA[2][128 * 32];
  __shared__ alignas(16) ushort sB[2][128 * 32];
  const int tid = threadIdx.x;
  const int lane = tid & 63, w = tid >> 6;
  const int m0 = blockIdx.y * 128, n0 = blockIdx.x * 128;
  const int NK = K >> 5;

  const int srow = w * 32 + (lane >> 2);
  const int scol = (lane & 3) * 8;
  const ushort* gA0 = A  + (size_t)(m0 + srow) * K + scol;
  const ushort* gB0 = BT + (size_t)(n0 + srow) * K + scol;

  const int wr = w >> 1, wc = w & 1;          // 2x2 wave grid, each 64x64
  const int g4 = lane >> 4, l16 = lane & 15;
  const int aoff = (wr * 64 + l16) * 32 + 8 * g4;
  const int boff = (wc * 64 + l16) * 32 + 8 * g4;

  f32x4 acc[4][4] = {};

  {
    const ushort* ga = gA0; const ushort* gb = gB0;
    GLOAD_LDS16(ga,            &sA[0][(w * 32) * 32]);
    GLOAD_LDS16(ga + 16 * K,   &sA[0][(w * 32 + 16) * 32]);
    GLOAD_LDS16(gb,            &sB[0][(w * 32) * 32]);
    GLOAD_LDS16(gb + 16 * K,   &sB[0][(w * 32 + 16) * 32]);
  }

  for (int kt = 0; kt < NK; ++kt) {
    __syncthreads();
    if (kt + 1 < NK) {
      int nb = (kt + 1) & 1;
      const ushort* ga = gA0 + (kt + 1) * 32;
      const ushort* gb = gB0 + (kt + 1) * 32;
      GLOAD_LDS16(ga,            &sA[nb][(w * 32) * 32]);
      GLOAD_LDS16(ga + 16 * K,   &sA[nb][(w * 32 + 16) * 32]);
      GLOAD_LDS16(gb,            &sB[nb][(w * 32) * 32]);
      GLOAD_LDS16(gb + 16 * K,   &sB[nb][(w * 32 + 16) * 32]);
    }
    const ushort* pa = &sA[kt & 1][aoff];
    const ushort* pb = &sB[kt & 1][boff];
    short8 af[4], bf[4];
#pragma unroll
    for (int i = 0; i < 4; ++i) {
      af[i] = *(const short8*)(pa + i * 16 * 32);
      bf[i] = *(const short8*)(pb + i * 16 * 32);
    }
#pragma unroll
    for (int mi = 0; mi < 4; ++mi)
#pragma unroll
      for (int ni = 0; ni < 4; ++ni)
        acc[mi][ni] = __builtin_amdgcn_mfma_f32_16x16x32_bf16(af[mi], bf[ni], acc[mi][ni], 0, 0, 0);
  }

#pragma unroll
  for (int mi = 0; mi < 4; ++mi) {
#pragma unroll
    for (int ni = 0; ni < 4; ++ni) {
#pragma unroll
      for (int r = 0; r < 4; ++r) {
        int m = m0 + wr * 64 + mi * 16 + g4 * 4 + r;
        int n = n0 + wc * 64 + ni * 16 + l16;
        float vv = acc[mi][ni][r];
        if (EPI == 2) {
          ((float*)Cout)[(size_t)m * N + n] = vv;
        } else {
          int b = m / S_, pos = m % S_;
          if (EPI == 0) {
            int dd = n & 63;
            if (SWZ) dd ^= (pos & 7) << 3;      // bake K-LDS row swizzle
            ushort hv = f2bf(vv * oscale);
            ((ushort*)Cout)[(((size_t)b * HN + (n >> 6)) * SP + pos) * 64 + dd] = hv;
          } else {
            int pp = pos;
            if (SWZ) pp ^= (n & 3) << 3;        // bake V-LDS row swizzle (within 32-k window)
            ushort hv = f2bf(vv);
            ((ushort*)Cout)[(((size_t)b * HN + (n >> 6)) * 64 + (n & 63)) * SP + pp] = hv;
          }
        }
      }
    }
  }
}

// ---------------- fused GQA attention: LDS-staged K/V (double-buffered) ----------------
// 1D grid 4096, XCD swizzle; block 256 = 4 waves, wave = 16 q-rows
// qp pre-scaled by 0.125*log2e; bias*log2e staged in LDS; p = exp2(s + bias')
// kp stored with d ^= (pos&7)<<3 (per-row XOR); vp stored with pos ^= (d&3)<<3
__global__ __launch_bounds__(256)
void attn_kernel(const ushort* __restrict__ qp, const ushort* __restrict__ kp,
                 const ushort* __restrict__ vpT, const float* __restrict__ rel,
                 ushort* __restrict__ ao) {
  __shared__ float sBias[1024];
  __shared__ alignas(16) ushort sK[2][32 * 64];   // [krow][d], rows pre-swizzled
  __shared__ alignas(16) ushort sV[2][64 * 32];   // [d][k-window], rows pre-swizzled
  __shared__ alignas(16) ushort sP[4][16 * 40];
  const int tid = threadIdx.x;
  const int blk = blockIdx.x;
  const int logical = (blk & 7) * 512 + (blk >> 3);     // bijective (4096 = 8*512)
  const int qt = logical & 7, head = (logical >> 3) & 15, b = logical >> 7;
  const int g = head >> 2;
  const float LOG2E = 1.44269504f;
  for (int t = tid; t < 1024; t += 256)
    sBias[t] = (t < 967) ? rel[t * 16 + head] * LOG2E : -1e30f;

  const int lane = tid & 63, w = tid >> 6;
  const int g4 = lane >> 4, l16 = lane & 15;
  const int qw = qt * 64 + w * 16;

  const ushort* qbase = qp + (((size_t)b * NH + head) * SP + qw + l16) * 64;
  short8 qf0 = *(const short8*)(qbase + 8 * g4);
  short8 qf1 = *(const short8*)(qbase + 32 + 8 * g4);

  // staging source pointers (linear copy of pre-swizzled layouts)
  const ushort* kSrc = kp  + ((size_t)b * 4 + g) * SP * 64 + (tid >> 3) * 64 + (tid & 7) * 8;
  const ushort* vSrc = vpT + ((size_t)b * 4 + g) * 64 * SP + (tid >> 2) * SP + (tid & 3) * 8;

  f32x4 acc[4] = {};
  float ps[4] = {0.f, 0.f, 0.f, 0.f};
  const int ib = l16 - (qw + g4 * 4) + 483;   // bias idx for r=0, k0=0
  ushort* sPw = &sP[w][0];

  // fragment LDS offsets (element units), matching the baked global swizzles
  const int kswz  = (l16 & 7) << 3;
  const int kOff0 = l16 * 64 + ((8 * g4) ^ kswz);        // k-rows l16, d 0-31
  const int kOff1 = l16 * 64 + ((32 + 8 * g4) ^ kswz);   // k-rows l16, d 32-63
  const int vOff  = l16 * 32 + 8 * (g4 ^ (l16 & 3));     // + nt*16*32

  GLOAD_LDS16(kSrc, &sK[0][w * 512]);
  GLOAD_LDS16(vSrc, &sV[0][w * 512]);

  for (int kt = 0; kt < 16; ++kt) {
    __syncthreads();                 // drains vmcnt: tile kt staged; buf[(kt+1)&1] free
    if (kt + 1 < 16) {
      GLOAD_LDS16(kSrc + (kt + 1) * 2048, &sK[(kt + 1) & 1][w * 512]);
      GLOAD_LDS16(vSrc + (kt + 1) * 32,   &sV[(kt + 1) & 1][w * 512]);
    }
    const ushort* sk = &sK[kt & 1][0];
    const ushort* sv = &sV[kt & 1][0];
    short8 kf0 = *(const short8*)(sk + kOff0);
    short8 kf1 = *(const short8*)(sk + kOff1);
    short8 kf2 = *(const short8*)(sk + 1024 + kOff0);
    short8 kf3 = *(const short8*)(sk + 1024 + kOff1);
    f32x4 s0 = {}, s1 = {};
    s0 = __builtin_amdgcn_mfma_f32_16x16x32_bf16(qf0, kf0, s0, 0, 0, 0);
    s0 = __builtin_amdgcn_mfma_f32_16x16x32_bf16(qf1, kf1, s0, 0, 0, 0);
    s1 = __builtin_amdgcn_mfma_f32_16x16x32_bf16(qf0, kf2, s1, 0, 0, 0);
    s1 = __builtin_amdgcn_mfma_f32_16x16x32_bf16(qf1, kf3, s1, 0, 0, 0);

    const int k0 = kt * 32;
#pragma unroll
    for (int r = 0; r < 4; ++r) {
      int i0 = ib + k0 - r;
      float p0 = __builtin_amdgcn_exp2f(s0[r] + sBias[i0]);
      float p1 = __builtin_amdgcn_exp2f(s1[r] + sBias[i0 + 16]);
      s0[r] = p0; s1[r] = p1;
      if (kt == 15) {
        p0 = (k0 + l16 < S_) ? p0 : 0.f;
        p1 = (k0 + 16 + l16 < S_) ? p1 : 0.f;
      }
      ps[r] += p0 + p1;
    }
#pragma unroll
    for (int r = 0; r < 4; ++r) {
      int row = g4 * 4 + r;
      sPw[row * 40 + l16]      = f2bf(s0[r]);
      sPw[row * 40 + 16 + l16] = f2bf(s1[r]);
    }
    short8 pf = *(const short8*)(sPw + l16 * 40 + 8 * g4);
#pragma unroll
    for (int nt = 0; nt < 4; ++nt) {
      short8 vf = *(const short8*)(sv + vOff + nt * 512);
      acc[nt] = __builtin_amdgcn_mfma_f32_16x16x32_bf16(pf, vf, acc[nt], 0, 0, 0);
    }
  }

  // row-sum reduce across the 16-lane group (once, outside the k-loop)
#pragma unroll
  for (int off = 1; off < 16; off <<= 1) {
#pragma unroll
    for (int r = 0; r < 4; ++r) ps[r] += __shfl_xor(ps[r], off, 64);
  }

#pragma unroll
  for (int r = 0; r < 4; ++r) {
    int q_abs = qw + g4 * 4 + r;
    if (q_abs < S_) {
      float inv = 1.f / ps[r];
#pragma unroll
      for (int nt = 0; nt < 4; ++nt) {
        int dd = nt * 16 + l16;
        ao[((size_t)b * S_ + q_abs) * 1024 + head * 64 + dd] = f2bf(acc[nt][r] * inv);
      }
    }
  }
}

extern "C" void kernel_launch(void* const* d_in, const int* in_sizes, int n_in,
                              void* d_out, int out_size, void* d_ws, size_t ws_size,
                              hipStream_t stream) {
  const float* query = (const float*)d_in[0];
  const float* key   = (const float*)d_in[1];
  const float* value = (const float*)d_in[2];
  const float* Wq    = (const float*)d_in[3];
  const float* Wk    = (const float*)d_in[4];
  const float* Wv    = (const float*)d_in[5];
  const float* Wo    = (const float*)d_in[6];
  const float* rel   = (const float*)d_in[7];

  char* ws = (char*)d_ws;
  size_t off = 0;
  auto alloc = [&](size_t bytes) { char* p = ws + off; off += (bytes + 255) & ~(size_t)255; return p; };

  const size_t MEelems = (size_t)M_ * E_;             // 15,859,712
  ushort* qb  = (ushort*)alloc(MEelems * 2);
  ushort* kb  = (ushort*)alloc(MEelems * 2);
  ushort* vb  = (ushort*)alloc(MEelems * 2);
  ushort* wqT = (ushort*)alloc((size_t)1024 * 1024 * 2);
  ushort* wkT = (ushort*)alloc((size_t)256 * 1024 * 2);
  ushort* wvT = (ushort*)alloc((size_t)256 * 1024 * 2);
  ushort* woT = (ushort*)alloc((size_t)1024 * 1024 * 2);
  ushort* qp  = (ushort*)alloc((size_t)B_ * NH * SP * 64 * 2);   // 32 MB
  ushort* kp  = (ushort*)alloc((size_t)B_ * 4 * SP * 64 * 2);    // 8 MB
  ushort* vp  = (ushort*)alloc((size_t)B_ * 4 * 64 * SP * 2);    // 8 MB
  ushort* ao  = (ushort*)alloc(MEelems * 2);

  const int n4 = (int)(MEelems / 4);
  cvt_f32_bf16<<<2048, 256, 0, stream>>>(query, qb, n4);
  cvt_f32_bf16<<<2048, 256, 0, stream>>>(key,   kb, n4);
  cvt_f32_bf16<<<2048, 256, 0, stream>>>(value, vb, n4);

  transpose_convert<<<dim3(32, 32), dim3(32, 8), 0, stream>>>(Wq, wqT, 1024, 1024);
  transpose_convert<<<dim3(8, 32),  dim3(32, 8), 0, stream>>>(Wk, wkT, 1024, 256);
  transpose_convert<<<dim3(8, 32),  dim3(32, 8), 0, stream>>>(Wv, wvT, 1024, 256);
  transpose_convert<<<dim3(32, 32), dim3(32, 8), 0, stream>>>(Wo, woT, 1024, 1024);

  // qp, kp, vp are contiguous in ws: one memset covers all three (32+8+8 MB)
  hipMemsetAsync(qp, 0, (size_t)B_ * NH * SP * 64 * 2 +
                        (size_t)B_ * 4 * SP * 64 * 2 +
                        (size_t)B_ * 4 * 64 * SP * 2, stream);

  const float QSCALE = 0.125f * 1.44269504f;   // fold 1/sqrt(D) and log2e into q
  gemm_bt<0,0><<<dim3(8, 121), 256, 0, stream>>>(qb, wqT, qp, 1024, 1024, NH, QSCALE);
  gemm_bt<0,1><<<dim3(2, 121), 256, 0, stream>>>(kb, wkT, kp, 256, 1024, 4, 1.0f);
  gemm_bt<1,1><<<dim3(2, 121), 256, 0, stream>>>(vb, wvT, vp, 256, 1024, 4, 1.0f);

  attn_kernel<<<4096, 256, 0, stream>>>(qp, kp, vp, rel, ao);

  gemm_bt<2,0><<<dim3(8, 121), 256, 0, stream>>>(ao, woT, d_out, 1024, 1024, 0, 1.0f);
}